// Round 2
// baseline (3002.412 us; speedup 1.0000x reference)
//
#include <hip/hip_runtime.h>

// Problem constants (fixed by the reference file)
constexpr int NN = 50000;   // nodes
constexpr int EE = 500000;  // edges
constexpr int FF = 128;     // features
constexpr int UU = 256;     // units
// K = 3 hops

// ---------------- degree / normalization ----------------

__global__ __launch_bounds__(256) void k_deg(const int* __restrict__ row,
                                             const float* __restrict__ ew,
                                             float* __restrict__ deg, int E) {
    int e = blockIdx.x * 256 + threadIdx.x;
    if (e < E) atomicAdd(&deg[row[e]], ew[e]);
}

__global__ __launch_bounds__(256) void k_dis(float* __restrict__ deg, int n) {
    int i = blockIdx.x * 256 + threadIdx.x;
    if (i < n) {
        float d = deg[i];
        deg[i] = (d > 0.f) ? (1.0f / sqrtf(fmaxf(d, 1e-12f))) : 0.f;
    }
}

__global__ __launch_bounds__(256) void k_norm(const int* __restrict__ row,
                                              const int* __restrict__ col,
                                              const float* __restrict__ ew,
                                              const float* __restrict__ dis,
                                              float* __restrict__ w, int E) {
    int e = blockIdx.x * 256 + threadIdx.x;
    if (e < E) w[e] = dis[row[e]] * ew[e] * dis[col[e]];
}

// ---------------- propagation ----------------

// hout = hin  (self-loop contribution, also serves as the zero-init)
__global__ __launch_bounds__(256) void k_copy4(const float4* __restrict__ in,
                                               float4* __restrict__ out, int n4) {
    int i = blockIdx.x * 256 + threadIdx.x;
    if (i < n4) out[i] = in[i];
}

// hout[col[e]] += hin[row[e]] * w[e]; one thread per (edge, 4-float chunk)
__global__ __launch_bounds__(256) void k_prop(const int* __restrict__ row,
                                              const int* __restrict__ col,
                                              const float* __restrict__ w,
                                              const float* __restrict__ hin,
                                              float* __restrict__ hout, int E) {
    int gid = blockIdx.x * 256 + threadIdx.x;
    int e = gid >> 5;          // FF/4 = 32 chunks per edge
    int c = gid & 31;
    if (e >= E) return;
    int r = row[e], cl = col[e];
    float we = w[e];
    const float4 v = *reinterpret_cast<const float4*>(hin + (size_t)r * FF + (c << 2));
    float* dst = hout + (size_t)cl * FF + (c << 2);
    atomicAdd(dst + 0, v.x * we);
    atomicAdd(dst + 1, v.y * we);
    atomicAdd(dst + 2, v.z * we);
    atomicAdd(dst + 3, v.w * we);
}

// ---------------- dense part ----------------

__global__ __launch_bounds__(256) void k_init_out(float4* __restrict__ out,
                                                  const float4* __restrict__ bias4,
                                                  int n4) {
    int i = blockIdx.x * 256 + threadIdx.x;
    if (i < n4) out[i] = bias4[i & 63];   // UU/4 = 64
}

// out[64-row tile] += h_tile[64x128] @ Wp[128x256]
// 256 threads: tc = t&63 -> 4 cols (float4), tr = t>>6 -> rows tr+4*i, i=0..15
__global__ __launch_bounds__(256) void k_gemm_acc(const float* __restrict__ h,
                                                  const float* __restrict__ Wp,
                                                  float* __restrict__ out, int nrows) {
    __shared__ float hs[64][128];
    const int t = threadIdx.x;
    const int brow = blockIdx.x * 64;

    // stage h tile (coalesced float4)
#pragma unroll
    for (int i = 0; i < 8; ++i) {
        int fi = t + 256 * i;           // [0, 2048)
        int r = fi >> 5, c4 = fi & 31;
        int gr = brow + r;
        float4 v = make_float4(0.f, 0.f, 0.f, 0.f);
        if (gr < nrows) v = *reinterpret_cast<const float4*>(h + (size_t)gr * FF + (c4 << 2));
        *reinterpret_cast<float4*>(&hs[r][c4 << 2]) = v;
    }
    __syncthreads();

    const int tc = t & 63;
    const int tr = t >> 6;
    float acc[16][4];
#pragma unroll
    for (int i = 0; i < 16; ++i) {
        acc[i][0] = 0.f; acc[i][1] = 0.f; acc[i][2] = 0.f; acc[i][3] = 0.f;
    }

    for (int k = 0; k < 128; k += 4) {
        float4 w0 = *reinterpret_cast<const float4*>(Wp + (size_t)(k + 0) * UU + (tc << 2));
        float4 w1 = *reinterpret_cast<const float4*>(Wp + (size_t)(k + 1) * UU + (tc << 2));
        float4 w2 = *reinterpret_cast<const float4*>(Wp + (size_t)(k + 2) * UU + (tc << 2));
        float4 w3 = *reinterpret_cast<const float4*>(Wp + (size_t)(k + 3) * UU + (tc << 2));
#pragma unroll
        for (int i = 0; i < 16; ++i) {
            float4 hv = *reinterpret_cast<const float4*>(&hs[tr + 4 * i][k]);
            acc[i][0] += hv.x * w0.x + hv.y * w1.x + hv.z * w2.x + hv.w * w3.x;
            acc[i][1] += hv.x * w0.y + hv.y * w1.y + hv.z * w2.y + hv.w * w3.y;
            acc[i][2] += hv.x * w0.z + hv.y * w1.z + hv.z * w2.z + hv.w * w3.z;
            acc[i][3] += hv.x * w0.w + hv.y * w1.w + hv.z * w2.w + hv.w * w3.w;
        }
    }

#pragma unroll
    for (int i = 0; i < 16; ++i) {
        int gr = brow + tr + 4 * i;
        if (gr < nrows) {
            float4* o = reinterpret_cast<float4*>(out + (size_t)gr * UU + (tc << 2));
            float4 cur = *o;
            cur.x += acc[i][0]; cur.y += acc[i][1];
            cur.z += acc[i][2]; cur.w += acc[i][3];
            *o = cur;
        }
    }
}

// ---------------- launch ----------------

extern "C" void kernel_launch(void* const* d_in, const int* in_sizes, int n_in,
                              void* d_out, int out_size, void* d_ws, size_t ws_size,
                              hipStream_t stream) {
    const float* x    = (const float*)d_in[0];
    const int*   ei   = (const int*)d_in[1];
    const float* ew   = (const float*)d_in[2];
    const float* Wk   = (const float*)d_in[3];   // [512, 256] row-major
    const float* bias = (const float*)d_in[4];
    float* out = (float*)d_out;

    const int* row = ei;
    const int* col = ei + EE;

    char* ws = (char*)d_ws;
    size_t off = 0;
    auto alloc = [&](size_t bytes) {
        size_t o = off;
        off += (bytes + 255) & ~(size_t)255;
        return o;
    };
    float* deg = (float*)(ws + alloc((size_t)NN * sizeof(float)));
    float* w   = (float*)(ws + alloc((size_t)EE * sizeof(float)));
    float* h1  = (float*)(ws + alloc((size_t)NN * FF * sizeof(float)));
    float* h2  = (float*)(ws + alloc((size_t)NN * FF * sizeof(float)));

    // normalization
    hipMemsetAsync(deg, 0, (size_t)NN * sizeof(float), stream);
    k_deg<<<(EE + 255) / 256, 256, 0, stream>>>(row, ew, deg, EE);
    k_dis<<<(NN + 255) / 256, 256, 0, stream>>>(deg, NN);
    k_norm<<<(EE + 255) / 256, 256, 0, stream>>>(row, col, ew, deg, w, EE);

    const int n4h = NN * FF / 4;                 // 1.6M float4
    const int gcopy = (n4h + 255) / 256;
    const int gprop = (EE * 32 + 255) / 256;     // 62500 blocks
    const int ggemm = (NN + 63) / 64;            // 782 blocks
    const int n4o = NN * UU / 4;
    const int ginit = (n4o + 255) / 256;

    // out = bias; out += x @ W0
    k_init_out<<<ginit, 256, 0, stream>>>((float4*)out, (const float4*)bias, n4o);
    k_gemm_acc<<<ggemm, 256, 0, stream>>>(x, Wk + 0 * FF * UU, out, NN);

    // hop 1: h1 = x + A x ; out += h1 @ W1
    k_copy4<<<gcopy, 256, 0, stream>>>((const float4*)x, (float4*)h1, n4h);
    k_prop<<<gprop, 256, 0, stream>>>(row, col, w, x, h1, EE);
    k_gemm_acc<<<ggemm, 256, 0, stream>>>(h1, Wk + 1 * FF * UU, out, NN);

    // hop 2: h2 = h1 + A h1 ; out += h2 @ W2
    k_copy4<<<gcopy, 256, 0, stream>>>((const float4*)h1, (float4*)h2, n4h);
    k_prop<<<gprop, 256, 0, stream>>>(row, col, w, h1, h2, EE);
    k_gemm_acc<<<ggemm, 256, 0, stream>>>(h2, Wk + 2 * FF * UU, out, NN);

    // hop 3: h1 = h2 + A h2 ; out += h1 @ W3   (reuse h1)
    k_copy4<<<gcopy, 256, 0, stream>>>((const float4*)h2, (float4*)h1, n4h);
    k_prop<<<gprop, 256, 0, stream>>>(row, col, w, h2, h1, EE);
    k_gemm_acc<<<ggemm, 256, 0, stream>>>(h1, Wk + 3 * FF * UU, out, NN);
}

// Round 3
// 774.339 us; speedup vs baseline: 3.8774x; 3.8774x over previous
//
#include <hip/hip_runtime.h>

// Problem constants (fixed by the reference file)
constexpr int NN = 50000;   // nodes
constexpr int EE = 500000;  // edges
constexpr int FF = 128;     // features
constexpr int UU = 256;     // units
// K = 3 hops

// ---------------- degree / col-count (fused) ----------------

__global__ __launch_bounds__(256) void k_degcnt(const int* __restrict__ row,
                                                const int* __restrict__ col,
                                                const float* __restrict__ ew,
                                                float* __restrict__ deg,
                                                int* __restrict__ cnt, int E) {
    int e = blockIdx.x * 256 + threadIdx.x;
    if (e < E) {
        atomicAdd(&deg[row[e]], ew[e]);
        atomicAdd(&cnt[col[e]], 1);
    }
}

__global__ __launch_bounds__(256) void k_dis(float* __restrict__ deg, int n) {
    int i = blockIdx.x * 256 + threadIdx.x;
    if (i < n) {
        float d = deg[i];
        deg[i] = (d > 0.f) ? (1.0f / sqrtf(fmaxf(d, 1e-12f))) : 0.f;
    }
}

__global__ __launch_bounds__(256) void k_norm(const int* __restrict__ row,
                                              const int* __restrict__ col,
                                              const float* __restrict__ ew,
                                              const float* __restrict__ dis,
                                              float* __restrict__ w, int E) {
    int e = blockIdx.x * 256 + threadIdx.x;
    if (e < E) w[e] = dis[row[e]] * ew[e] * dis[col[e]];
}

// ---------------- CSR build ----------------

// single-block exclusive scan over cnt[0..NN) -> offs[0..NN], cursor copy
__global__ __launch_bounds__(256) void k_scan(const int* __restrict__ cnt,
                                              int* __restrict__ offs,
                                              int* __restrict__ cursor) {
    __shared__ int ts[256];
    const int t = threadIdx.x;
    const int chunk = (NN + 255) / 256;  // 196
    const int beg = t * chunk;
    const int end = min(beg + chunk, NN);
    int s = 0;
    for (int i = beg; i < end; ++i) s += cnt[i];
    ts[t] = s;
    __syncthreads();
    // Hillis-Steele inclusive scan over 256 thread-sums
    for (int d = 1; d < 256; d <<= 1) {
        int v = ts[t];
        int o = (t >= d) ? ts[t - d] : 0;
        __syncthreads();
        ts[t] = v + o;
        __syncthreads();
    }
    int run = ts[t] - s;  // exclusive prefix of this chunk
    for (int i = beg; i < end; ++i) {
        offs[i] = run;
        cursor[i] = run;
        run += cnt[i];
    }
    if (t == 255) offs[NN] = run;  // == EE
}

// scatter edges into destination-sorted order
__global__ __launch_bounds__(256) void k_scatter(const int* __restrict__ row,
                                                 const int* __restrict__ col,
                                                 const float* __restrict__ w,
                                                 int* __restrict__ cursor,
                                                 int* __restrict__ rows_s,
                                                 float* __restrict__ w_s, int E) {
    int e = blockIdx.x * 256 + threadIdx.x;
    if (e < E) {
        int c = col[e];
        int slot = atomicAdd(&cursor[c], 1);
        rows_s[slot] = row[e];
        w_s[slot] = w[e];
    }
}

// ---------------- propagation (CSR, atomic-free) ----------------

// one wave (64 lanes) per destination node; lane holds float2 of features
// hout[dst] = hin[dst] + sum_e w_s[e] * hin[rows_s[e]]
__global__ __launch_bounds__(256) void k_prop_csr(const int* __restrict__ offs,
                                                  const int* __restrict__ rows_s,
                                                  const float* __restrict__ w_s,
                                                  const float* __restrict__ hin,
                                                  float* __restrict__ hout) {
    int wid = (blockIdx.x * 256 + threadIdx.x) >> 6;  // dst node
    int lane = threadIdx.x & 63;
    if (wid >= NN) return;
    const int beg = offs[wid];
    const int end = offs[wid + 1];

    float2 acc = *reinterpret_cast<const float2*>(hin + (size_t)wid * FF + lane * 2);
    for (int e = beg; e < end; ++e) {
        int r = rows_s[e];
        float wv = w_s[e];
        float2 v = *reinterpret_cast<const float2*>(hin + (size_t)r * FF + lane * 2);
        acc.x += v.x * wv;
        acc.y += v.y * wv;
    }
    *reinterpret_cast<float2*>(hout + (size_t)wid * FF + lane * 2) = acc;
}

// ---------------- dense part ----------------

__global__ __launch_bounds__(256) void k_init_out(float4* __restrict__ out,
                                                  const float4* __restrict__ bias4,
                                                  int n4) {
    int i = blockIdx.x * 256 + threadIdx.x;
    if (i < n4) out[i] = bias4[i & 63];   // UU/4 = 64
}

// out[64-row tile] += h_tile[64x128] @ Wp[128x256]
__global__ __launch_bounds__(256) void k_gemm_acc(const float* __restrict__ h,
                                                  const float* __restrict__ Wp,
                                                  float* __restrict__ out, int nrows) {
    __shared__ float hs[64][128];
    const int t = threadIdx.x;
    const int brow = blockIdx.x * 64;

#pragma unroll
    for (int i = 0; i < 8; ++i) {
        int fi = t + 256 * i;           // [0, 2048)
        int r = fi >> 5, c4 = fi & 31;
        int gr = brow + r;
        float4 v = make_float4(0.f, 0.f, 0.f, 0.f);
        if (gr < nrows) v = *reinterpret_cast<const float4*>(h + (size_t)gr * FF + (c4 << 2));
        *reinterpret_cast<float4*>(&hs[r][c4 << 2]) = v;
    }
    __syncthreads();

    const int tc = t & 63;
    const int tr = t >> 6;
    float acc[16][4];
#pragma unroll
    for (int i = 0; i < 16; ++i) {
        acc[i][0] = 0.f; acc[i][1] = 0.f; acc[i][2] = 0.f; acc[i][3] = 0.f;
    }

    for (int k = 0; k < 128; k += 4) {
        float4 w0 = *reinterpret_cast<const float4*>(Wp + (size_t)(k + 0) * UU + (tc << 2));
        float4 w1 = *reinterpret_cast<const float4*>(Wp + (size_t)(k + 1) * UU + (tc << 2));
        float4 w2 = *reinterpret_cast<const float4*>(Wp + (size_t)(k + 2) * UU + (tc << 2));
        float4 w3 = *reinterpret_cast<const float4*>(Wp + (size_t)(k + 3) * UU + (tc << 2));
#pragma unroll
        for (int i = 0; i < 16; ++i) {
            float4 hv = *reinterpret_cast<const float4*>(&hs[tr + 4 * i][k]);
            acc[i][0] += hv.x * w0.x + hv.y * w1.x + hv.z * w2.x + hv.w * w3.x;
            acc[i][1] += hv.x * w0.y + hv.y * w1.y + hv.z * w2.y + hv.w * w3.y;
            acc[i][2] += hv.x * w0.z + hv.y * w1.z + hv.z * w2.z + hv.w * w3.z;
            acc[i][3] += hv.x * w0.w + hv.y * w1.w + hv.z * w2.w + hv.w * w3.w;
        }
    }

#pragma unroll
    for (int i = 0; i < 16; ++i) {
        int gr = brow + tr + 4 * i;
        if (gr < nrows) {
            float4* o = reinterpret_cast<float4*>(out + (size_t)gr * UU + (tc << 2));
            float4 cur = *o;
            cur.x += acc[i][0]; cur.y += acc[i][1];
            cur.z += acc[i][2]; cur.w += acc[i][3];
            *o = cur;
        }
    }
}

// ---------------- launch ----------------

extern "C" void kernel_launch(void* const* d_in, const int* in_sizes, int n_in,
                              void* d_out, int out_size, void* d_ws, size_t ws_size,
                              hipStream_t stream) {
    const float* x    = (const float*)d_in[0];
    const int*   ei   = (const int*)d_in[1];
    const float* ew   = (const float*)d_in[2];
    const float* Wk   = (const float*)d_in[3];   // [512, 256] row-major
    const float* bias = (const float*)d_in[4];
    float* out = (float*)d_out;

    const int* row = ei;
    const int* col = ei + EE;

    char* ws = (char*)d_ws;
    size_t off = 0;
    auto alloc = [&](size_t bytes) {
        size_t o = off;
        off += (bytes + 255) & ~(size_t)255;
        return o;
    };
    float* deg    = (float*)(ws + alloc((size_t)NN * sizeof(float)));
    float* w      = (float*)(ws + alloc((size_t)EE * sizeof(float)));
    int*   cnt    = (int*)  (ws + alloc((size_t)NN * sizeof(int)));
    int*   cursor = (int*)  (ws + alloc((size_t)NN * sizeof(int)));
    int*   offs   = (int*)  (ws + alloc((size_t)(NN + 1) * sizeof(int)));
    int*   rows_s = (int*)  (ws + alloc((size_t)EE * sizeof(int)));
    float* w_s    = (float*)(ws + alloc((size_t)EE * sizeof(float)));
    float* h1     = (float*)(ws + alloc((size_t)NN * FF * sizeof(float)));
    float* h2     = (float*)(ws + alloc((size_t)NN * FF * sizeof(float)));

    const int geb = (EE + 255) / 256;
    const int gnb = (NN + 255) / 256;

    // normalization + CSR build
    hipMemsetAsync(deg, 0, (size_t)NN * sizeof(float), stream);
    hipMemsetAsync(cnt, 0, (size_t)NN * sizeof(int), stream);
    k_degcnt<<<geb, 256, 0, stream>>>(row, col, ew, deg, cnt, EE);
    k_dis<<<gnb, 256, 0, stream>>>(deg, NN);
    k_norm<<<geb, 256, 0, stream>>>(row, col, ew, deg, w, EE);
    k_scan<<<1, 256, 0, stream>>>(cnt, offs, cursor);
    k_scatter<<<geb, 256, 0, stream>>>(row, col, w, cursor, rows_s, w_s, EE);

    const int gprop = (NN * 64 + 255) / 256;     // 1 wave per node, 4 waves/block
    const int ggemm = (NN + 63) / 64;            // 782 blocks
    const int n4o = NN * UU / 4;
    const int ginit = (n4o + 255) / 256;

    // out = bias; out += x @ W0
    k_init_out<<<ginit, 256, 0, stream>>>((float4*)out, (const float4*)bias, n4o);
    k_gemm_acc<<<ggemm, 256, 0, stream>>>(x, Wk + 0 * FF * UU, out, NN);

    // hop 1: h1 = x + A x ; out += h1 @ W1
    k_prop_csr<<<gprop, 256, 0, stream>>>(offs, rows_s, w_s, x, h1);
    k_gemm_acc<<<ggemm, 256, 0, stream>>>(h1, Wk + 1 * FF * UU, out, NN);

    // hop 2: h2 = h1 + A h1 ; out += h2 @ W2
    k_prop_csr<<<gprop, 256, 0, stream>>>(offs, rows_s, w_s, h1, h2);
    k_gemm_acc<<<ggemm, 256, 0, stream>>>(h2, Wk + 2 * FF * UU, out, NN);

    // hop 3: h1 = h2 + A h2 ; out += h1 @ W3   (reuse h1)
    k_prop_csr<<<gprop, 256, 0, stream>>>(offs, rows_s, w_s, h2, h1);
    k_gemm_acc<<<ggemm, 256, 0, stream>>>(h1, Wk + 3 * FF * UU, out, NN);
}

// Round 6
// 391.982 us; speedup vs baseline: 7.6596x; 1.9754x over previous
//
#include <hip/hip_runtime.h>

// Problem constants (fixed by the reference file)
constexpr int NN = 50000;   // nodes
constexpr int EE = 500000;  // edges
constexpr int FF = 128;     // features
constexpr int UU = 256;     // units
constexpr int KK = 512;     // F*(K+1) concat width
constexpr int NB = (NN + 255) / 256;  // 196 scan blocks

using bf16x8 = __attribute__((ext_vector_type(8))) short;
using f32x4  = __attribute__((ext_vector_type(4))) float;

__device__ inline float bf2f(unsigned short b) {
    unsigned u = (unsigned)b << 16; float f; __builtin_memcpy(&f, &u, 4); return f;
}
__device__ inline unsigned short f2bf(float f) {  // round-to-nearest-even
    unsigned u; __builtin_memcpy(&u, &f, 4);
    u = u + 0x7fffu + ((u >> 16) & 1u);
    return (unsigned short)(u >> 16);
}

// ---------------- degree / col-count (fused) ----------------

__global__ __launch_bounds__(256) void k_degcnt(const int* __restrict__ row,
                                                const int* __restrict__ col,
                                                const float* __restrict__ ew,
                                                float* __restrict__ deg,
                                                int* __restrict__ cnt, int E) {
    int e = blockIdx.x * 256 + threadIdx.x;
    if (e < E) {
        atomicAdd(&deg[row[e]], ew[e]);
        atomicAdd(&cnt[col[e]], 1);
    }
}

__global__ __launch_bounds__(256) void k_dis(float* __restrict__ deg, int n) {
    int i = blockIdx.x * 256 + threadIdx.x;
    if (i < n) {
        float d = deg[i];
        deg[i] = (d > 0.f) ? (1.0f / sqrtf(fmaxf(d, 1e-12f))) : 0.f;
    }
}

// ---------------- parallel scan (3 kernels) ----------------

__global__ __launch_bounds__(256) void k_scan1(const int* __restrict__ cnt,
                                               int* __restrict__ offs,
                                               int* __restrict__ bsum) {
    const int t = threadIdx.x;
    const int gid = blockIdx.x * 256 + t;
    int v = (gid < NN) ? cnt[gid] : 0;
    __shared__ int ts[256];
    ts[t] = v; __syncthreads();
    for (int d = 1; d < 256; d <<= 1) {
        int a = ts[t]; int b = (t >= d) ? ts[t - d] : 0;
        __syncthreads(); ts[t] = a + b; __syncthreads();
    }
    if (gid < NN) offs[gid] = ts[t] - v;          // exclusive within block
    if (t == 255) bsum[blockIdx.x] = ts[255];     // block total
}

__global__ __launch_bounds__(256) void k_scan2(int* __restrict__ bsum) {
    const int t = threadIdx.x;
    int v = (t < NB) ? bsum[t] : 0;
    __shared__ int ts[256];
    ts[t] = v; __syncthreads();
    for (int d = 1; d < 256; d <<= 1) {
        int a = ts[t]; int b = (t >= d) ? ts[t - d] : 0;
        __syncthreads(); ts[t] = a + b; __syncthreads();
    }
    if (t < NB) bsum[t] = ts[t] - v;              // exclusive block prefix
}

__global__ __launch_bounds__(256) void k_scan3(int* __restrict__ offs,
                                               int* __restrict__ cursor,
                                               const int* __restrict__ bsum) {
    const int gid = blockIdx.x * 256 + threadIdx.x;
    if (gid < NN) {
        int val = offs[gid] + bsum[blockIdx.x];
        offs[gid] = val;
        cursor[gid] = val;
    }
    if (gid == 0) offs[NN] = EE;
}

// ---------------- scatter (norm fused in) ----------------

__global__ __launch_bounds__(256) void k_scatter(const int* __restrict__ row,
                                                 const int* __restrict__ col,
                                                 const float* __restrict__ ew,
                                                 const float* __restrict__ dis,
                                                 int* __restrict__ cursor,
                                                 int* __restrict__ rows_s,
                                                 float* __restrict__ w_s, int E) {
    int e = blockIdx.x * 256 + threadIdx.x;
    if (e < E) {
        int r = row[e], c = col[e];
        int slot = atomicAdd(&cursor[c], 1);
        rows_s[slot] = r;
        w_s[slot] = dis[r] * ew[e] * dis[c];
    }
}

// ---------------- casts ----------------

// x [N,128] f32 -> Hcat slice 0 (bf16, row stride KK)
__global__ __launch_bounds__(256) void k_xcast(const float4* __restrict__ x4,
                                               unsigned short* __restrict__ H) {
    int i = blockIdx.x * 256 + threadIdx.x;
    if (i < NN * 32) {
        int n = i >> 5, c4 = i & 31;
        float4 v = x4[i];
        ushort4 o;
        o.x = f2bf(v.x); o.y = f2bf(v.y); o.z = f2bf(v.z); o.w = f2bf(v.w);
        *reinterpret_cast<ushort4*>(H + (size_t)n * KK + c4 * 4) = o;
    }
}

// W [512,256] f32 -> Wt [256,512] bf16 (transposed)
__global__ __launch_bounds__(256) void k_wcast(const float* __restrict__ W,
                                               unsigned short* __restrict__ Wt) {
    int t = blockIdx.x * 256 + threadIdx.x;
    if (t < KK * UU) {
        int k = t >> 8, c = t & 255;
        Wt[(size_t)c * KK + k] = f2bf(W[t]);
    }
}

// ---------------- propagation (CSR, bf16, atomic-free) ----------------

// one wave per dst node; lane holds 2 bf16 features (u32)
__global__ __launch_bounds__(256) void k_prop(const int* __restrict__ offs,
                                              const int* __restrict__ rows_s,
                                              const float* __restrict__ w_s,
                                              unsigned short* __restrict__ H,
                                              int sin, int sout) {
    int wid = (blockIdx.x * 256 + threadIdx.x) >> 6;
    int lane = threadIdx.x & 63;
    if (wid >= NN) return;
    const unsigned short* bin = H + (size_t)sin * FF;
    unsigned self = *reinterpret_cast<const unsigned*>(bin + (size_t)wid * KK + lane * 2);
    float a0 = bf2f((unsigned short)self);
    float a1 = bf2f((unsigned short)(self >> 16));
    const int beg = offs[wid], end = offs[wid + 1];
    for (int e = beg; e < end; ++e) {
        int r = rows_s[e];
        float wv = w_s[e];
        unsigned v = *reinterpret_cast<const unsigned*>(bin + (size_t)r * KK + lane * 2);
        a0 += bf2f((unsigned short)v) * wv;
        a1 += bf2f((unsigned short)(v >> 16)) * wv;
    }
    unsigned o = (unsigned)f2bf(a0) | ((unsigned)f2bf(a1) << 16);
    *reinterpret_cast<unsigned*>(H + (size_t)sout * FF + (size_t)wid * KK + lane * 2) = o;
}

// ---------------- fused MFMA GEMM: out = Hcat @ Wk + bias ----------------
// block: 256 thr = 4 waves; tile 64 rows x 256 cols; wave w -> cols w*64..
// K = 512 in 16 steps of 32. A[64x32], Bt[256x32] staged in LDS (pitch 56).

__global__ __launch_bounds__(256) void k_gemm(const unsigned short* __restrict__ H,
                                              const unsigned short* __restrict__ Wt,
                                              const float* __restrict__ bias,
                                              float* __restrict__ out) {
    __shared__ __align__(16) short As[64][56];
    __shared__ __align__(16) short Bs[256][56];
    const int t = threadIdx.x;
    const int lane = t & 63;
    const int wv = t >> 6;
    const int wcol = wv * 64;
    const int brow = blockIdx.x * 64;
    const int rA = t >> 2, quad = t & 3;   // staging: one 16B piece per thread (A)

    f32x4 acc[4][4] = {};

    for (int ks = 0; ks < 16; ++ks) {
        const int koff = ks * 32;
        // stage A tile [64][32]
        {
            int gr = brow + rA;
            int4 v = make_int4(0, 0, 0, 0);
            if (gr < NN)
                v = *reinterpret_cast<const int4*>(H + (size_t)gr * KK + koff + quad * 8);
            *reinterpret_cast<int4*>(&As[rA][quad * 8]) = v;
        }
        // stage Bt tile [256][32] (4 pieces per thread)
#pragma unroll
        for (int i = 0; i < 4; ++i) {
            int c = (t >> 2) + 64 * i;
            int4 v = *reinterpret_cast<const int4*>(Wt + (size_t)c * KK + koff + quad * 8);
            *reinterpret_cast<int4*>(&Bs[c][quad * 8]) = v;
        }
        __syncthreads();

        bf16x8 af[4], bf[4];
#pragma unroll
        for (int fm = 0; fm < 4; ++fm)
            af[fm] = *reinterpret_cast<const bf16x8*>(&As[fm * 16 + (lane & 15)][(lane >> 4) * 8]);
#pragma unroll
        for (int fn = 0; fn < 4; ++fn)
            bf[fn] = *reinterpret_cast<const bf16x8*>(&Bs[wcol + fn * 16 + (lane & 15)][(lane >> 4) * 8]);
#pragma unroll
        for (int fm = 0; fm < 4; ++fm)
#pragma unroll
            for (int fn = 0; fn < 4; ++fn)
                acc[fm][fn] = __builtin_amdgcn_mfma_f32_16x16x32_bf16(af[fm], bf[fn], acc[fm][fn], 0, 0, 0);
        __syncthreads();
    }

    // epilogue: D mapping col=lane&15, row=(lane>>4)*4+r
#pragma unroll
    for (int fn = 0; fn < 4; ++fn) {
        int col = wcol + fn * 16 + (lane & 15);
        float bs = bias[col];
#pragma unroll
        for (int fm = 0; fm < 4; ++fm) {
#pragma unroll
            for (int r4 = 0; r4 < 4; ++r4) {
                int grow = brow + fm * 16 + (lane >> 4) * 4 + r4;
                if (grow < NN)
                    out[(size_t)grow * UU + col] = acc[fm][fn][r4] + bs;
            }
        }
    }
}

// ---------------- launch ----------------

extern "C" void kernel_launch(void* const* d_in, const int* in_sizes, int n_in,
                              void* d_out, int out_size, void* d_ws, size_t ws_size,
                              hipStream_t stream) {
    const float* x    = (const float*)d_in[0];
    const int*   ei   = (const int*)d_in[1];
    const float* ew   = (const float*)d_in[2];
    const float* Wk   = (const float*)d_in[3];   // [512, 256] row-major
    const float* bias = (const float*)d_in[4];
    float* out = (float*)d_out;

    const int* row = ei;
    const int* col = ei + EE;

    char* ws = (char*)d_ws;
    size_t off = 0;
    auto alloc = [&](size_t bytes) {
        size_t o = off;
        off += (bytes + 255) & ~(size_t)255;
        return o;
    };
    float*          deg    = (float*)(ws + alloc((size_t)NN * sizeof(float)));
    int*            cnt    = (int*)  (ws + alloc((size_t)NN * sizeof(int)));
    int*            cursor = (int*)  (ws + alloc((size_t)NN * sizeof(int)));
    int*            offs   = (int*)  (ws + alloc((size_t)(NN + 1) * sizeof(int)));
    int*            bsum   = (int*)  (ws + alloc((size_t)256 * sizeof(int)));
    int*            rows_s = (int*)  (ws + alloc((size_t)EE * sizeof(int)));
    float*          w_s    = (float*)(ws + alloc((size_t)EE * sizeof(float)));
    unsigned short* Hcat   = (unsigned short*)(ws + alloc((size_t)NN * KK * sizeof(short)));
    unsigned short* Wt     = (unsigned short*)(ws + alloc((size_t)KK * UU * sizeof(short)));

    const int geb = (EE + 255) / 256;

    // normalization + CSR build
    hipMemsetAsync(deg, 0, (size_t)NN * sizeof(float), stream);
    hipMemsetAsync(cnt, 0, (size_t)NN * sizeof(int), stream);
    k_degcnt<<<geb, 256, 0, stream>>>(row, col, ew, deg, cnt, EE);
    k_dis<<<NB, 256, 0, stream>>>(deg, NN);
    k_scan1<<<NB, 256, 0, stream>>>(cnt, offs, bsum);
    k_scan2<<<1, 256, 0, stream>>>(bsum);
    k_scan3<<<NB, 256, 0, stream>>>(offs, cursor, bsum);
    k_scatter<<<geb, 256, 0, stream>>>(row, col, ew, deg, cursor, rows_s, w_s, EE);

    // casts
    k_xcast<<<(NN * 32 + 255) / 256, 256, 0, stream>>>((const float4*)x, Hcat);
    k_wcast<<<(KK * UU + 255) / 256, 256, 0, stream>>>(Wk, Wt);

    // propagation: slice s -> s+1
    const int gprop = (NN * 64 + 255) / 256;
    k_prop<<<gprop, 256, 0, stream>>>(offs, rows_s, w_s, Hcat, 0, 1);
    k_prop<<<gprop, 256, 0, stream>>>(offs, rows_s, w_s, Hcat, 1, 2);
    k_prop<<<gprop, 256, 0, stream>>>(offs, rows_s, w_s, Hcat, 2, 3);

    // fused GEMM + bias
    k_gemm<<<(NN + 63) / 64, 256, 0, stream>>>(Hcat, Wt, bias, out);
}

// Round 7
// 303.329 us; speedup vs baseline: 9.8982x; 1.2923x over previous
//
#include <hip/hip_runtime.h>

// Problem constants (fixed by the reference file)
constexpr int NN = 50000;   // nodes
constexpr int EE = 500000;  // edges
constexpr int FF = 128;     // features
constexpr int UU = 256;     // units
constexpr int KK = 512;     // F*(K+1) concat width
constexpr int NB = (NN + 255) / 256;  // 196 scan blocks

using bf16x8 = __attribute__((ext_vector_type(8))) short;
using f32x4  = __attribute__((ext_vector_type(4))) float;

__device__ inline float bf2f(unsigned short b) {
    unsigned u = (unsigned)b << 16; float f; __builtin_memcpy(&f, &u, 4); return f;
}
__device__ inline unsigned short f2bf(float f) {  // round-to-nearest-even
    unsigned u; __builtin_memcpy(&u, &f, 4);
    u = u + 0x7fffu + ((u >> 16) & 1u);
    return (unsigned short)(u >> 16);
}

typedef __attribute__((address_space(1))) const void GASV;
typedef __attribute__((address_space(3))) void LASV;
__device__ inline void gload_lds16(const void* g, void* l) {
    // async 16B/lane global->LDS; LDS dest = wave-uniform base + lane*16
    __builtin_amdgcn_global_load_lds((GASV*)g, (LASV*)l, 16, 0, 0);
}

// ---------------- degree / col-count (fused) ----------------

__global__ __launch_bounds__(256) void k_degcnt(const int* __restrict__ row,
                                                const int* __restrict__ col,
                                                const float* __restrict__ ew,
                                                float* __restrict__ deg,
                                                int* __restrict__ cnt, int E) {
    int e = blockIdx.x * 256 + threadIdx.x;
    if (e < E) {
        atomicAdd(&deg[row[e]], ew[e]);
        atomicAdd(&cnt[col[e]], 1);
    }
}

// ---------------- parallel scan (3 kernels; k_dis fused into scan1) -------

__global__ __launch_bounds__(256) void k_scan1(const int* __restrict__ cnt,
                                               int* __restrict__ offs,
                                               int* __restrict__ bsum,
                                               float* __restrict__ deg) {
    const int t = threadIdx.x;
    const int gid = blockIdx.x * 256 + t;
    // fused deg -> deg^{-1/2}
    if (gid < NN) {
        float d = deg[gid];
        deg[gid] = (d > 0.f) ? (1.0f / sqrtf(fmaxf(d, 1e-12f))) : 0.f;
    }
    int v = (gid < NN) ? cnt[gid] : 0;
    __shared__ int ts[256];
    ts[t] = v; __syncthreads();
    for (int d = 1; d < 256; d <<= 1) {
        int a = ts[t]; int b = (t >= d) ? ts[t - d] : 0;
        __syncthreads(); ts[t] = a + b; __syncthreads();
    }
    if (gid < NN) offs[gid] = ts[t] - v;          // exclusive within block
    if (t == 255) bsum[blockIdx.x] = ts[255];     // block total
}

__global__ __launch_bounds__(256) void k_scan2(int* __restrict__ bsum) {
    const int t = threadIdx.x;
    int v = (t < NB) ? bsum[t] : 0;
    __shared__ int ts[256];
    ts[t] = v; __syncthreads();
    for (int d = 1; d < 256; d <<= 1) {
        int a = ts[t]; int b = (t >= d) ? ts[t - d] : 0;
        __syncthreads(); ts[t] = a + b; __syncthreads();
    }
    if (t < NB) bsum[t] = ts[t] - v;              // exclusive block prefix
}

__global__ __launch_bounds__(256) void k_scan3(int* __restrict__ offs,
                                               int* __restrict__ cursor,
                                               const int* __restrict__ bsum) {
    const int gid = blockIdx.x * 256 + threadIdx.x;
    if (gid < NN) {
        int val = offs[gid] + bsum[blockIdx.x];
        offs[gid] = val;
        cursor[gid] = val;
    }
    if (gid == 0) offs[NN] = EE;
}

// ---------------- scatter (norm fused in) ----------------

__global__ __launch_bounds__(256) void k_scatter(const int* __restrict__ row,
                                                 const int* __restrict__ col,
                                                 const float* __restrict__ ew,
                                                 const float* __restrict__ dis,
                                                 int* __restrict__ cursor,
                                                 int* __restrict__ rows_s,
                                                 float* __restrict__ w_s, int E) {
    int e = blockIdx.x * 256 + threadIdx.x;
    if (e < E) {
        int r = row[e], c = col[e];
        int slot = atomicAdd(&cursor[c], 1);
        rows_s[slot] = r;
        w_s[slot] = dis[r] * ew[e] * dis[c];
    }
}

// ---------------- casts ----------------

// x [N,128] f32 -> Hcat slice 0 (bf16, row stride KK)
__global__ __launch_bounds__(256) void k_xcast(const float4* __restrict__ x4,
                                               unsigned short* __restrict__ H) {
    int i = blockIdx.x * 256 + threadIdx.x;
    if (i < NN * 32) {
        int n = i >> 5, c4 = i & 31;
        float4 v = x4[i];
        ushort4 o;
        o.x = f2bf(v.x); o.y = f2bf(v.y); o.z = f2bf(v.z); o.w = f2bf(v.w);
        *reinterpret_cast<ushort4*>(H + (size_t)n * KK + c4 * 4) = o;
    }
}

// W [512,256] f32 -> Wt [256,512] bf16 (transposed)
__global__ __launch_bounds__(256) void k_wcast(const float* __restrict__ W,
                                               unsigned short* __restrict__ Wt) {
    int t = blockIdx.x * 256 + threadIdx.x;
    if (t < KK * UU) {
        int k = t >> 8, c = t & 255;
        Wt[(size_t)c * KK + k] = f2bf(W[t]);
    }
}

// ---------------- propagation (CSR, bf16, atomic-free) ----------------

// one wave per dst node; lane holds 2 bf16 features (u32); edge loop x4 MLP
__global__ __launch_bounds__(256) void k_prop(const int* __restrict__ offs,
                                              const int* __restrict__ rows_s,
                                              const float* __restrict__ w_s,
                                              unsigned short* __restrict__ H,
                                              int sin, int sout) {
    int wid = (blockIdx.x * 256 + threadIdx.x) >> 6;
    int lane = threadIdx.x & 63;
    if (wid >= NN) return;
    const unsigned short* bin = H + (size_t)sin * FF;
    unsigned self = *reinterpret_cast<const unsigned*>(bin + (size_t)wid * KK + lane * 2);
    float a0 = bf2f((unsigned short)self);
    float a1 = bf2f((unsigned short)(self >> 16));
    const int beg = offs[wid], end = offs[wid + 1];
    int e = beg;
    for (; e + 4 <= end; e += 4) {
        int r0 = rows_s[e], r1 = rows_s[e + 1], r2 = rows_s[e + 2], r3 = rows_s[e + 3];
        float w0 = w_s[e], w1 = w_s[e + 1], w2 = w_s[e + 2], w3 = w_s[e + 3];
        unsigned v0 = *reinterpret_cast<const unsigned*>(bin + (size_t)r0 * KK + lane * 2);
        unsigned v1 = *reinterpret_cast<const unsigned*>(bin + (size_t)r1 * KK + lane * 2);
        unsigned v2 = *reinterpret_cast<const unsigned*>(bin + (size_t)r2 * KK + lane * 2);
        unsigned v3 = *reinterpret_cast<const unsigned*>(bin + (size_t)r3 * KK + lane * 2);
        a0 += bf2f((unsigned short)v0) * w0 + bf2f((unsigned short)v1) * w1
            + bf2f((unsigned short)v2) * w2 + bf2f((unsigned short)v3) * w3;
        a1 += bf2f((unsigned short)(v0 >> 16)) * w0 + bf2f((unsigned short)(v1 >> 16)) * w1
            + bf2f((unsigned short)(v2 >> 16)) * w2 + bf2f((unsigned short)(v3 >> 16)) * w3;
    }
    for (; e < end; ++e) {
        int r = rows_s[e];
        float wv = w_s[e];
        unsigned v = *reinterpret_cast<const unsigned*>(bin + (size_t)r * KK + lane * 2);
        a0 += bf2f((unsigned short)v) * wv;
        a1 += bf2f((unsigned short)(v >> 16)) * wv;
    }
    unsigned o = (unsigned)f2bf(a0) | ((unsigned)f2bf(a1) << 16);
    *reinterpret_cast<unsigned*>(H + (size_t)sout * FF + (size_t)wid * KK + lane * 2) = o;
}

// ---------------- fused MFMA GEMM: out = Hcat @ Wk + bias ----------------
// 782 blocks = 391 row-tiles x 2 col-tiles. Tile 128x128, BK=64, double-buffered
// LDS via global_load_lds w16 with XOR-swizzled SOURCE (linear LDS dest).
// 4 waves in 2x2 grid; wave = 64x64 out; 16 f32x4 acc.

__global__ __launch_bounds__(256, 2) void k_gemm(const unsigned short* __restrict__ H,
                                                 const unsigned short* __restrict__ Wt,
                                                 const float* __restrict__ bias,
                                                 float* __restrict__ out) {
    __shared__ __align__(16) char As[2][128 * 128];  // [buf][row 0..127][128B = 64 bf16]
    __shared__ __align__(16) char Bs[2][128 * 128];  // [buf][col 0..127][128B]
    const int t = threadIdx.x;
    const int lane = t & 63;
    const int wv = t >> 6;
    const int wm = wv >> 1;          // row half
    const int wn = wv & 1;           // col half
    const int brow = (blockIdx.x >> 1) * 128;
    const int bcol = (blockIdx.x & 1) * 128;

    const int r8  = lane >> 3;          // row within 8-row chunk
    const int b16 = (lane & 7) * 16;    // byte within 128B row

    f32x4 acc[4][4] = {};

    auto stage = [&](int buf, int ks) {
        // 32 chunks of 1KB: 16 A (rows), 16 B (cols); wave wv does chunks wv*8..wv*8+7
#pragma unroll
        for (int i = 0; i < 8; ++i) {
            int c = wv * 8 + i;
            if (c < 16) {
                int r = c * 8 + r8;                       // tile row 0..127
                int gr = brow + r; if (gr >= NN) gr = NN - 1;
                const char* src = (const char*)H + (size_t)gr * (KK * 2) + ks * 128
                                  + (b16 ^ ((r & 7) << 4));
                gload_lds16(src, &As[buf][c * 1024]);
            } else {
                int cc = (c - 16) * 8 + r8;               // tile col 0..127
                int gc = bcol + cc;
                const char* src = (const char*)Wt + (size_t)gc * (KK * 2) + ks * 128
                                  + (b16 ^ ((cc & 7) << 4));
                gload_lds16(src, &Bs[buf][(c - 16) * 1024]);
            }
        }
    };

    auto compute = [&](int buf) {
        bf16x8 af[2][4], bfr[2][4];
#pragma unroll
        for (int kk = 0; kk < 2; ++kk) {
#pragma unroll
            for (int f = 0; f < 4; ++f) {
                int r = wm * 64 + f * 16 + (lane & 15);
                int ba = (kk * 64 + (lane >> 4) * 16) ^ ((r & 7) << 4);
                af[kk][f] = *reinterpret_cast<const bf16x8*>(&As[buf][r * 128 + ba]);
                int cc = wn * 64 + f * 16 + (lane & 15);
                int bb = (kk * 64 + (lane >> 4) * 16) ^ ((cc & 7) << 4);
                bfr[kk][f] = *reinterpret_cast<const bf16x8*>(&Bs[buf][cc * 128 + bb]);
            }
        }
#pragma unroll
        for (int kk = 0; kk < 2; ++kk)
#pragma unroll
            for (int fm = 0; fm < 4; ++fm)
#pragma unroll
                for (int fn = 0; fn < 4; ++fn)
                    acc[fm][fn] = __builtin_amdgcn_mfma_f32_16x16x32_bf16(
                        af[kk][fm], bfr[kk][fn], acc[fm][fn], 0, 0, 0);
    };

    stage(0, 0);
    __syncthreads();                       // drains vmcnt before barrier
    for (int ks = 0; ks < 8; ++ks) {
        if (ks < 7) stage((ks + 1) & 1, ks + 1);  // prefetch overlaps MFMA below
        compute(ks & 1);
        __syncthreads();
    }

    // epilogue: D mapping col=lane&15, row=(lane>>4)*4+r4  (verified round-3)
#pragma unroll
    for (int fn = 0; fn < 4; ++fn) {
        int col = bcol + wn * 64 + fn * 16 + (lane & 15);
        float bs = bias[col];
#pragma unroll
        for (int fm = 0; fm < 4; ++fm) {
#pragma unroll
            for (int r4 = 0; r4 < 4; ++r4) {
                int grow = brow + wm * 64 + fm * 16 + (lane >> 4) * 4 + r4;
                if (grow < NN)
                    out[(size_t)grow * UU + col] = acc[fm][fn][r4] + bs;
            }
        }
    }
}

// ---------------- launch ----------------

extern "C" void kernel_launch(void* const* d_in, const int* in_sizes, int n_in,
                              void* d_out, int out_size, void* d_ws, size_t ws_size,
                              hipStream_t stream) {
    const float* x    = (const float*)d_in[0];
    const int*   ei   = (const int*)d_in[1];
    const float* ew   = (const float*)d_in[2];
    const float* Wk   = (const float*)d_in[3];   // [512, 256] row-major
    const float* bias = (const float*)d_in[4];
    float* out = (float*)d_out;

    const int* row = ei;
    const int* col = ei + EE;

    char* ws = (char*)d_ws;
    size_t off = 0;
    auto alloc = [&](size_t bytes) {
        size_t o = off;
        off += (bytes + 255) & ~(size_t)255;
        return o;
    };
    float*          deg    = (float*)(ws + alloc((size_t)NN * sizeof(float)));
    int*            cnt    = (int*)  (ws + alloc((size_t)NN * sizeof(int)));
    int*            cursor = (int*)  (ws + alloc((size_t)NN * sizeof(int)));
    int*            offs   = (int*)  (ws + alloc((size_t)(NN + 1) * sizeof(int)));
    int*            bsum   = (int*)  (ws + alloc((size_t)256 * sizeof(int)));
    int*            rows_s = (int*)  (ws + alloc((size_t)EE * sizeof(int)));
    float*          w_s    = (float*)(ws + alloc((size_t)EE * sizeof(float)));
    unsigned short* Hcat   = (unsigned short*)(ws + alloc((size_t)NN * KK * sizeof(short)));
    unsigned short* Wt     = (unsigned short*)(ws + alloc((size_t)KK * UU * sizeof(short)));

    const int geb = (EE + 255) / 256;

    // normalization + CSR build
    hipMemsetAsync(deg, 0, (size_t)NN * sizeof(float), stream);
    hipMemsetAsync(cnt, 0, (size_t)NN * sizeof(int), stream);
    k_degcnt<<<geb, 256, 0, stream>>>(row, col, ew, deg, cnt, EE);
    k_scan1<<<NB, 256, 0, stream>>>(cnt, offs, bsum, deg);
    k_scan2<<<1, 256, 0, stream>>>(bsum);
    k_scan3<<<NB, 256, 0, stream>>>(offs, cursor, bsum);
    k_scatter<<<geb, 256, 0, stream>>>(row, col, ew, deg, cursor, rows_s, w_s, EE);

    // casts
    k_xcast<<<(NN * 32 + 255) / 256, 256, 0, stream>>>((const float4*)x, Hcat);
    k_wcast<<<(KK * UU + 255) / 256, 256, 0, stream>>>(Wk, Wt);

    // propagation: slice s -> s+1
    const int gprop = (NN * 64 + 255) / 256;
    k_prop<<<gprop, 256, 0, stream>>>(offs, rows_s, w_s, Hcat, 0, 1);
    k_prop<<<gprop, 256, 0, stream>>>(offs, rows_s, w_s, Hcat, 1, 2);
    k_prop<<<gprop, 256, 0, stream>>>(offs, rows_s, w_s, Hcat, 2, 3);

    // fused GEMM + bias (391 row-tiles x 2 col-tiles)
    k_gemm<<<391 * 2, 256, 0, stream>>>(Hcat, Wt, bias, out);
}

// Round 8
// 276.959 us; speedup vs baseline: 10.8406x; 1.0952x over previous
//
#include <hip/hip_runtime.h>

// Problem constants (fixed by the reference file)
constexpr int NN = 50000;   // nodes
constexpr int EE = 500000;  // edges
constexpr int FF = 128;     // features
constexpr int UU = 256;     // units
constexpr int KK = 512;     // F*(K+1) concat width
constexpr int NB = (NN + 255) / 256;  // 196 scan blocks

using bf16x8 = __attribute__((ext_vector_type(8))) short;
using f32x4  = __attribute__((ext_vector_type(4))) float;

__device__ inline float bf2f(unsigned short b) {
    unsigned u = (unsigned)b << 16; float f; __builtin_memcpy(&f, &u, 4); return f;
}
__device__ inline unsigned short f2bf(float f) {  // round-to-nearest-even
    unsigned u; __builtin_memcpy(&u, &f, 4);
    u = u + 0x7fffu + ((u >> 16) & 1u);
    return (unsigned short)(u >> 16);
}

typedef __attribute__((address_space(1))) const void GASV;
typedef __attribute__((address_space(3))) void LASV;
__device__ inline void gload_lds16(const void* g, void* l) {
    __builtin_amdgcn_global_load_lds((GASV*)g, (LASV*)l, 16, 0, 0);
}

// -------- fused: degree/count atomics (every 3rd block) + x->bf16 cast --------

__global__ __launch_bounds__(256) void k_deg_x(const int* __restrict__ row,
                                               const int* __restrict__ col,
                                               const float* __restrict__ ew,
                                               float* __restrict__ deg,
                                               int* __restrict__ cnt,
                                               const float4* __restrict__ x4,
                                               unsigned short* __restrict__ H) {
    const int i = blockIdx.x * 256 + threadIdx.x;
    // xcast part: 1.6M float4 elems -> Hcat slice 0
    if (i < NN * 32) {
        int n = i >> 5, c4 = i & 31;
        float4 v = x4[i];
        ushort4 o;
        o.x = f2bf(v.x); o.y = f2bf(v.y); o.z = f2bf(v.z); o.w = f2bf(v.w);
        *reinterpret_cast<ushort4*>(H + (size_t)n * KK + c4 * 4) = o;
    }
    // edge atomics: blocks 0,3,6,... handle a 256-edge slice (interleaved w/ xcast blocks)
    if (blockIdx.x % 3 == 0) {
        int e = (blockIdx.x / 3) * 256 + threadIdx.x;
        if (e < EE) {
            atomicAdd(&deg[row[e]], ew[e]);
            atomicAdd(&cnt[col[e]], 1);
        }
    }
}

// ---------------- parallel scan (3 kernels; deg^-1/2 fused into scan1) -------

__global__ __launch_bounds__(256) void k_scan1(const int* __restrict__ cnt,
                                               int* __restrict__ offs,
                                               int* __restrict__ bsum,
                                               float* __restrict__ deg) {
    const int t = threadIdx.x;
    const int gid = blockIdx.x * 256 + t;
    if (gid < NN) {
        float d = deg[gid];
        deg[gid] = (d > 0.f) ? (1.0f / sqrtf(fmaxf(d, 1e-12f))) : 0.f;
    }
    int v = (gid < NN) ? cnt[gid] : 0;
    __shared__ int ts[256];
    ts[t] = v; __syncthreads();
    for (int d = 1; d < 256; d <<= 1) {
        int a = ts[t]; int b = (t >= d) ? ts[t - d] : 0;
        __syncthreads(); ts[t] = a + b; __syncthreads();
    }
    if (gid < NN) offs[gid] = ts[t] - v;
    if (t == 255) bsum[blockIdx.x] = ts[255];
}

__global__ __launch_bounds__(256) void k_scan2(int* __restrict__ bsum) {
    const int t = threadIdx.x;
    int v = (t < NB) ? bsum[t] : 0;
    __shared__ int ts[256];
    ts[t] = v; __syncthreads();
    for (int d = 1; d < 256; d <<= 1) {
        int a = ts[t]; int b = (t >= d) ? ts[t - d] : 0;
        __syncthreads(); ts[t] = a + b; __syncthreads();
    }
    if (t < NB) bsum[t] = ts[t] - v;
}

__global__ __launch_bounds__(256) void k_scan3(int* __restrict__ offs,
                                               int* __restrict__ cursor,
                                               const int* __restrict__ bsum) {
    const int gid = blockIdx.x * 256 + threadIdx.x;
    if (gid < NN) {
        int val = offs[gid] + bsum[blockIdx.x];
        offs[gid] = val;
        cursor[gid] = val;
    }
    if (gid == 0) offs[NN] = EE;
}

// ---- scatter: packed (row, w) 8B record per edge; W-transpose-cast fused ----

__global__ __launch_bounds__(256) void k_scatter(const int* __restrict__ row,
                                                 const int* __restrict__ col,
                                                 const float* __restrict__ ew,
                                                 const float* __restrict__ dis,
                                                 int* __restrict__ cursor,
                                                 uint2* __restrict__ edata,
                                                 const float* __restrict__ W,
                                                 unsigned short* __restrict__ Wt) {
    const int e = blockIdx.x * 256 + threadIdx.x;
    if (e < EE) {
        int r = row[e], c = col[e];
        int slot = atomicAdd(&cursor[c], 1);
        float wv = dis[r] * ew[e] * dis[c];
        uint2 d; d.x = (unsigned)r; __builtin_memcpy(&d.y, &wv, 4);
        edata[slot] = d;
    }
    // wcast: W [512,256] f32 -> Wt [256,512] bf16 (first 512 blocks)
    if (e < KK * UU) {
        int k = e >> 8, c = e & 255;
        Wt[(size_t)c * KK + k] = f2bf(W[e]);
    }
}

// ---------------- propagation: 4 edges in flight per wave ----------------
// wave per dst node; 4 groups x 16 lanes; lane holds 8 bf16 (16B) of the row.

__global__ __launch_bounds__(256) void k_prop(const int* __restrict__ offs,
                                              const uint2* __restrict__ edata,
                                              unsigned short* __restrict__ H,
                                              int sin, int sout) {
    const int wid = (blockIdx.x * 256 + threadIdx.x) >> 6;  // dst node (grid exact)
    const int lane = threadIdx.x & 63;
    const int g = lane >> 4;          // edge group 0..3
    const int sl = lane & 15;         // 16B chunk within row

    const unsigned short* bin = H + (size_t)sin * FF;
    const unsigned short* rowp = bin + (size_t)wid * KK + sl * 8;

    float a[8];
    {   // self contribution (weight 1), added by group 0 only
        uint4 s4 = *reinterpret_cast<const uint4*>(rowp);
        const unsigned sw[4] = {s4.x, s4.y, s4.z, s4.w};
#pragma unroll
        for (int j = 0; j < 8; ++j) {
            float v = bf2f((unsigned short)(sw[j >> 1] >> ((j & 1) * 16)));
            a[j] = (g == 0) ? v : 0.f;
        }
    }

    const int beg = offs[wid], end = offs[wid + 1];
    int e = beg + g;
    for (; e + 4 < end; e += 8) {     // unroll 2 (edges e and e+4)
        uint2 d0 = edata[e], d1 = edata[e + 4];
        float w0, w1; __builtin_memcpy(&w0, &d0.y, 4); __builtin_memcpy(&w1, &d1.y, 4);
        uint4 v0 = *reinterpret_cast<const uint4*>(bin + (size_t)d0.x * KK + sl * 8);
        uint4 v1 = *reinterpret_cast<const uint4*>(bin + (size_t)d1.x * KK + sl * 8);
        const unsigned u0[4] = {v0.x, v0.y, v0.z, v0.w};
        const unsigned u1[4] = {v1.x, v1.y, v1.z, v1.w};
#pragma unroll
        for (int j = 0; j < 8; ++j)
            a[j] += bf2f((unsigned short)(u0[j >> 1] >> ((j & 1) * 16))) * w0
                  + bf2f((unsigned short)(u1[j >> 1] >> ((j & 1) * 16))) * w1;
    }
    if (e < end) {
        uint2 d0 = edata[e];
        float w0; __builtin_memcpy(&w0, &d0.y, 4);
        uint4 v0 = *reinterpret_cast<const uint4*>(bin + (size_t)d0.x * KK + sl * 8);
        const unsigned u0[4] = {v0.x, v0.y, v0.z, v0.w};
#pragma unroll
        for (int j = 0; j < 8; ++j)
            a[j] += bf2f((unsigned short)(u0[j >> 1] >> ((j & 1) * 16))) * w0;
    }

    // combine the 4 groups
#pragma unroll
    for (int j = 0; j < 8; ++j) {
        a[j] += __shfl_xor(a[j], 16);
        a[j] += __shfl_xor(a[j], 32);
    }

    if (lane < 16) {
        uint4 o;
        o.x = (unsigned)f2bf(a[0]) | ((unsigned)f2bf(a[1]) << 16);
        o.y = (unsigned)f2bf(a[2]) | ((unsigned)f2bf(a[3]) << 16);
        o.z = (unsigned)f2bf(a[4]) | ((unsigned)f2bf(a[5]) << 16);
        o.w = (unsigned)f2bf(a[6]) | ((unsigned)f2bf(a[7]) << 16);
        *reinterpret_cast<uint4*>(H + (size_t)sout * FF + (size_t)wid * KK + sl * 8) = o;
    }
}

// ---------------- fused MFMA GEMM: out = Hcat @ Wk + bias ----------------
// 128x128 tile, BK=64, double-buffered global_load_lds w16, XOR-swizzled source.

__global__ __launch_bounds__(256, 2) void k_gemm(const unsigned short* __restrict__ H,
                                                 const unsigned short* __restrict__ Wt,
                                                 const float* __restrict__ bias,
                                                 float* __restrict__ out) {
    __shared__ __align__(16) char As[2][128 * 128];
    __shared__ __align__(16) char Bs[2][128 * 128];
    const int t = threadIdx.x;
    const int lane = t & 63;
    const int wv = t >> 6;
    const int wm = wv >> 1;
    const int wn = wv & 1;
    const int brow = (blockIdx.x >> 1) * 128;
    const int bcol = (blockIdx.x & 1) * 128;

    const int r8  = lane >> 3;
    const int b16 = (lane & 7) * 16;

    f32x4 acc[4][4] = {};

    auto stage = [&](int buf, int ks) {
#pragma unroll
        for (int i = 0; i < 8; ++i) {
            int c = wv * 8 + i;
            if (c < 16) {
                int r = c * 8 + r8;
                int gr = brow + r; if (gr >= NN) gr = NN - 1;
                const char* src = (const char*)H + (size_t)gr * (KK * 2) + ks * 128
                                  + (b16 ^ ((r & 7) << 4));
                gload_lds16(src, &As[buf][c * 1024]);
            } else {
                int cc = (c - 16) * 8 + r8;
                int gc = bcol + cc;
                const char* src = (const char*)Wt + (size_t)gc * (KK * 2) + ks * 128
                                  + (b16 ^ ((cc & 7) << 4));
                gload_lds16(src, &Bs[buf][(c - 16) * 1024]);
            }
        }
    };

    auto compute = [&](int buf) {
        bf16x8 af[2][4], bfr[2][4];
#pragma unroll
        for (int kk = 0; kk < 2; ++kk) {
#pragma unroll
            for (int f = 0; f < 4; ++f) {
                int r = wm * 64 + f * 16 + (lane & 15);
                int ba = (kk * 64 + (lane >> 4) * 16) ^ ((r & 7) << 4);
                af[kk][f] = *reinterpret_cast<const bf16x8*>(&As[buf][r * 128 + ba]);
                int cc = wn * 64 + f * 16 + (lane & 15);
                int bb = (kk * 64 + (lane >> 4) * 16) ^ ((cc & 7) << 4);
                bfr[kk][f] = *reinterpret_cast<const bf16x8*>(&Bs[buf][cc * 128 + bb]);
            }
        }
#pragma unroll
        for (int kk = 0; kk < 2; ++kk)
#pragma unroll
            for (int fm = 0; fm < 4; ++fm)
#pragma unroll
                for (int fn = 0; fn < 4; ++fn)
                    acc[fm][fn] = __builtin_amdgcn_mfma_f32_16x16x32_bf16(
                        af[kk][fm], bfr[kk][fn], acc[fm][fn], 0, 0, 0);
    };

    stage(0, 0);
    __syncthreads();
    for (int ks = 0; ks < 8; ++ks) {
        if (ks < 7) stage((ks + 1) & 1, ks + 1);
        compute(ks & 1);
        __syncthreads();
    }

#pragma unroll
    for (int fn = 0; fn < 4; ++fn) {
        int col = bcol + wn * 64 + fn * 16 + (lane & 15);
        float bs = bias[col];
#pragma unroll
        for (int fm = 0; fm < 4; ++fm) {
#pragma unroll
            for (int r4 = 0; r4 < 4; ++r4) {
                int grow = brow + wm * 64 + fm * 16 + (lane >> 4) * 4 + r4;
                if (grow < NN)
                    out[(size_t)grow * UU + col] = acc[fm][fn][r4] + bs;
            }
        }
    }
}

// ---------------- launch ----------------

extern "C" void kernel_launch(void* const* d_in, const int* in_sizes, int n_in,
                              void* d_out, int out_size, void* d_ws, size_t ws_size,
                              hipStream_t stream) {
    const float* x    = (const float*)d_in[0];
    const int*   ei   = (const int*)d_in[1];
    const float* ew   = (const float*)d_in[2];
    const float* Wk   = (const float*)d_in[3];   // [512, 256] row-major
    const float* bias = (const float*)d_in[4];
    float* out = (float*)d_out;

    const int* row = ei;
    const int* col = ei + EE;

    char* ws = (char*)d_ws;
    size_t off = 0;
    auto alloc = [&](size_t bytes) {
        size_t o = off;
        off += (bytes + 255) & ~(size_t)255;
        return o;
    };
    float*          deg    = (float*)(ws + alloc((size_t)NN * sizeof(float)));
    int*            cnt    = (int*)  (ws + alloc((size_t)NN * sizeof(int)));
    int*            cursor = (int*)  (ws + alloc((size_t)NN * sizeof(int)));
    int*            offs   = (int*)  (ws + alloc((size_t)(NN + 1) * sizeof(int)));
    int*            bsum   = (int*)  (ws + alloc((size_t)256 * sizeof(int)));
    uint2*          edata  = (uint2*)(ws + alloc((size_t)EE * sizeof(uint2)));
    unsigned short* Hcat   = (unsigned short*)(ws + alloc((size_t)NN * KK * sizeof(short)));
    unsigned short* Wt     = (unsigned short*)(ws + alloc((size_t)KK * UU * sizeof(short)));

    hipMemsetAsync(deg, 0, (size_t)NN * sizeof(float), stream);
    hipMemsetAsync(cnt, 0, (size_t)NN * sizeof(int), stream);

    // fused degree/count atomics + xcast (atomic blocks interleaved every 3rd)
    k_deg_x<<<(NN * 32 + 255) / 256, 256, 0, stream>>>(row, col, ew, deg, cnt,
                                                       (const float4*)x, Hcat);
    k_scan1<<<NB, 256, 0, stream>>>(cnt, offs, bsum, deg);
    k_scan2<<<1, 256, 0, stream>>>(bsum);
    k_scan3<<<NB, 256, 0, stream>>>(offs, cursor, bsum);
    k_scatter<<<(EE + 255) / 256, 256, 0, stream>>>(row, col, ew, deg, cursor,
                                                    edata, Wk, Wt);

    // propagation: slice s -> s+1 (grid exact: 50000 waves)
    const int gprop = NN / 4;
    k_prop<<<gprop, 256, 0, stream>>>(offs, edata, Hcat, 0, 1);
    k_prop<<<gprop, 256, 0, stream>>>(offs, edata, Hcat, 1, 2);
    k_prop<<<gprop, 256, 0, stream>>>(offs, edata, Hcat, 2, 3);

    // fused GEMM + bias (391 row-tiles x 2 col-tiles)
    k_gemm<<<391 * 2, 256, 0, stream>>>(Hcat, Wt, bias, out);
}

// Round 13
// 262.325 us; speedup vs baseline: 11.4454x; 1.0558x over previous
//
#include <hip/hip_runtime.h>

// Problem constants (fixed by the reference file)
constexpr int NN = 50000;   // nodes
constexpr int EE = 500000;  // edges
constexpr int FF = 128;     // features
constexpr int UU = 256;     // units
constexpr int KK = 512;     // F*(K+1) concat width
constexpr int NB = (NN + 255) / 256;  // 196 scan blocks
constexpr int PS = 32;      // counter pad stride (ints/floats) = 128B line

using bf16x8 = __attribute__((ext_vector_type(8))) short;
using f32x4  = __attribute__((ext_vector_type(4))) float;

__device__ inline float bf2f(unsigned short b) {
    unsigned u = (unsigned)b << 16; float f; __builtin_memcpy(&f, &u, 4); return f;
}
__device__ inline unsigned short f2bf(float f) {  // round-to-nearest-even
    unsigned u; __builtin_memcpy(&u, &f, 4);
    u = u + 0x7fffu + ((u >> 16) & 1u);
    return (unsigned short)(u >> 16);
}

typedef __attribute__((address_space(1))) const void GASV;
typedef __attribute__((address_space(3))) void LASV;
__device__ inline void gload_lds16(const void* g, void* l) {
    __builtin_amdgcn_global_load_lds((GASV*)g, (LASV*)l, 16, 0, 0);
}

// ---- fused: padded-line atomics (every 3rd block) + x->bf16 cast ----
// counters padded 1-per-128B-line: spreads 1M atomics over ~100K lines.

__global__ __launch_bounds__(256) void k_deg_x(const int* __restrict__ row,
                                               const int* __restrict__ col,
                                               const float* __restrict__ ew,
                                               float* __restrict__ deg_p,
                                               int* __restrict__ cnt_p,
                                               int* __restrict__ slot,
                                               const float4* __restrict__ x4,
                                               unsigned short* __restrict__ H) {
    const int i = blockIdx.x * 256 + threadIdx.x;
    if (i < NN * 32) {
        int n = i >> 5, c4 = i & 31;
        float4 v = x4[i];
        ushort4 o;
        o.x = f2bf(v.x); o.y = f2bf(v.y); o.z = f2bf(v.z); o.w = f2bf(v.w);
        *reinterpret_cast<ushort4*>(H + (size_t)n * KK + c4 * 4) = o;
    }
    if (blockIdx.x % 3 == 0) {
        int e = (blockIdx.x / 3) * 256 + threadIdx.x;
        if (e < EE) {
            atomicAdd(&deg_p[(size_t)row[e] * PS], ew[e]);
            slot[e] = atomicAdd(&cnt_p[(size_t)col[e] * PS], 1);  // slot = old count
        }
    }
}

// ---------------- parallel scan (padded cnt in; dis + offs out) -------------

__global__ __launch_bounds__(256) void k_scan1(const int* __restrict__ cnt_p,
                                               const float* __restrict__ deg_p,
                                               float* __restrict__ dis,
                                               int* __restrict__ offs,
                                               int* __restrict__ bsum) {
    const int t = threadIdx.x;
    const int gid = blockIdx.x * 256 + t;
    if (gid < NN) {
        float d = deg_p[(size_t)gid * PS];
        dis[gid] = (d > 0.f) ? (1.0f / sqrtf(fmaxf(d, 1e-12f))) : 0.f;
    }
    int v = (gid < NN) ? cnt_p[(size_t)gid * PS] : 0;
    __shared__ int ts[256];
    ts[t] = v; __syncthreads();
    for (int d = 1; d < 256; d <<= 1) {
        int a = ts[t]; int b = (t >= d) ? ts[t - d] : 0;
        __syncthreads(); ts[t] = a + b; __syncthreads();
    }
    if (gid < NN) offs[gid] = ts[t] - v;
    if (t == 255) bsum[blockIdx.x] = ts[255];
}

__global__ __launch_bounds__(256) void k_scan2(int* __restrict__ bsum) {
    const int t = threadIdx.x;
    int v = (t < NB) ? bsum[t] : 0;
    __shared__ int ts[256];
    ts[t] = v; __syncthreads();
    for (int d = 1; d < 256; d <<= 1) {
        int a = ts[t]; int b = (t >= d) ? ts[t - d] : 0;
        __syncthreads(); ts[t] = a + b; __syncthreads();
    }
    if (t < NB) bsum[t] = ts[t] - v;
}

__global__ __launch_bounds__(256) void k_scan3(int* __restrict__ offs,
                                               const int* __restrict__ bsum) {
    const int gid = blockIdx.x * 256 + threadIdx.x;
    if (gid < NN) offs[gid] += bsum[blockIdx.x];
    if (gid == 0) offs[NN] = EE;
}

// ---- scatter: atomic-free (slot from phase 1); W-transpose-cast fused ----

__global__ __launch_bounds__(256) void k_scatter(const int* __restrict__ row,
                                                 const int* __restrict__ col,
                                                 const float* __restrict__ ew,
                                                 const float* __restrict__ dis,
                                                 const int* __restrict__ offs,
                                                 const int* __restrict__ slot,
                                                 uint2* __restrict__ edata,
                                                 const float* __restrict__ W,
                                                 unsigned short* __restrict__ Wt) {
    const int e = blockIdx.x * 256 + threadIdx.x;
    if (e < EE) {
        int r = row[e], c = col[e];
        int sl = offs[c] + slot[e];
        float wv = dis[r] * ew[e] * dis[c];
        uint2 d; d.x = (unsigned)r; __builtin_memcpy(&d.y, &wv, 4);
        edata[sl] = d;
    }
    if (e < KK * UU) {
        int k = e >> 8, c = e & 255;
        Wt[(size_t)c * KK + k] = f2bf(W[e]);
    }
}

// ---------------- propagation: 4 edges in flight per wave ----------------

__global__ __launch_bounds__(256) void k_prop(const int* __restrict__ offs,
                                              const uint2* __restrict__ edata,
                                              unsigned short* __restrict__ H,
                                              int sin, int sout) {
    const int wid = (blockIdx.x * 256 + threadIdx.x) >> 6;
    const int lane = threadIdx.x & 63;
    const int g = lane >> 4;
    const int sl = lane & 15;

    const unsigned short* bin = H + (size_t)sin * FF;
    const unsigned short* rowp = bin + (size_t)wid * KK + sl * 8;

    float a[8];
    {
        uint4 s4 = *reinterpret_cast<const uint4*>(rowp);
        const unsigned sw[4] = {s4.x, s4.y, s4.z, s4.w};
#pragma unroll
        for (int j = 0; j < 8; ++j) {
            float v = bf2f((unsigned short)(sw[j >> 1] >> ((j & 1) * 16)));
            a[j] = (g == 0) ? v : 0.f;
        }
    }

    const int beg = offs[wid], end = offs[wid + 1];
    int e = beg + g;
    for (; e + 4 < end; e += 8) {
        uint2 d0 = edata[e], d1 = edata[e + 4];
        float w0, w1; __builtin_memcpy(&w0, &d0.y, 4); __builtin_memcpy(&w1, &d1.y, 4);
        uint4 v0 = *reinterpret_cast<const uint4*>(bin + (size_t)d0.x * KK + sl * 8);
        uint4 v1 = *reinterpret_cast<const uint4*>(bin + (size_t)d1.x * KK + sl * 8);
        const unsigned u0[4] = {v0.x, v0.y, v0.z, v0.w};
        const unsigned u1[4] = {v1.x, v1.y, v1.z, v1.w};
#pragma unroll
        for (int j = 0; j < 8; ++j)
            a[j] += bf2f((unsigned short)(u0[j >> 1] >> ((j & 1) * 16))) * w0
                  + bf2f((unsigned short)(u1[j >> 1] >> ((j & 1) * 16))) * w1;
    }
    if (e < end) {
        uint2 d0 = edata[e];
        float w0; __builtin_memcpy(&w0, &d0.y, 4);
        uint4 v0 = *reinterpret_cast<const uint4*>(bin + (size_t)d0.x * KK + sl * 8);
        const unsigned u0[4] = {v0.x, v0.y, v0.z, v0.w};
#pragma unroll
        for (int j = 0; j < 8; ++j)
            a[j] += bf2f((unsigned short)(u0[j >> 1] >> ((j & 1) * 16))) * w0;
    }

#pragma unroll
    for (int j = 0; j < 8; ++j) {
        a[j] += __shfl_xor(a[j], 16);
        a[j] += __shfl_xor(a[j], 32);
    }

    if (lane < 16) {
        uint4 o;
        o.x = (unsigned)f2bf(a[0]) | ((unsigned)f2bf(a[1]) << 16);
        o.y = (unsigned)f2bf(a[2]) | ((unsigned)f2bf(a[3]) << 16);
        o.z = (unsigned)f2bf(a[4]) | ((unsigned)f2bf(a[5]) << 16);
        o.w = (unsigned)f2bf(a[6]) | ((unsigned)f2bf(a[7]) << 16);
        *reinterpret_cast<uint4*>(H + (size_t)sout * FF + (size_t)wid * KK + sl * 8) = o;
    }
}

// ---------------- fused MFMA GEMM: out = Hcat @ Wk + bias ----------------

__global__ __launch_bounds__(256, 2) void k_gemm(const unsigned short* __restrict__ H,
                                                 const unsigned short* __restrict__ Wt,
                                                 const float* __restrict__ bias,
                                                 float* __restrict__ out) {
    __shared__ __align__(16) char As[2][128 * 128];
    __shared__ __align__(16) char Bs[2][128 * 128];
    const int t = threadIdx.x;
    const int lane = t & 63;
    const int wv = t >> 6;
    const int wm = wv >> 1;
    const int wn = wv & 1;
    const int brow = (blockIdx.x >> 1) * 128;
    const int bcol = (blockIdx.x & 1) * 128;

    const int r8  = lane >> 3;
    const int b16 = (lane & 7) * 16;

    f32x4 acc[4][4] = {};

    auto stage = [&](int buf, int ks) {
#pragma unroll
        for (int i = 0; i < 8; ++i) {
            int c = wv * 8 + i;
            if (c < 16) {
                int r = c * 8 + r8;
                int gr = brow + r; if (gr >= NN) gr = NN - 1;
                const char* src = (const char*)H + (size_t)gr * (KK * 2) + ks * 128
                                  + (b16 ^ ((r & 7) << 4));
                gload_lds16(src, &As[buf][c * 1024]);
            } else {
                int cc = (c - 16) * 8 + r8;
                int gc = bcol + cc;
                const char* src = (const char*)Wt + (size_t)gc * (KK * 2) + ks * 128
                                  + (b16 ^ ((cc & 7) << 4));
                gload_lds16(src, &Bs[buf][(c - 16) * 1024]);
            }
        }
    };

    auto compute = [&](int buf) {
        bf16x8 af[2][4], bfr[2][4];
#pragma unroll
        for (int kk = 0; kk < 2; ++kk) {
#pragma unroll
            for (int f = 0; f < 4; ++f) {
                int r = wm * 64 + f * 16 + (lane & 15);
                int ba = (kk * 64 + (lane >> 4) * 16) ^ ((r & 7) << 4);
                af[kk][f] = *reinterpret_cast<const bf16x8*>(&As[buf][r * 128 + ba]);
                int cc = wn * 64 + f * 16 + (lane & 15);
                int bb = (kk * 64 + (lane >> 4) * 16) ^ ((cc & 7) << 4);
                bfr[kk][f] = *reinterpret_cast<const bf16x8*>(&Bs[buf][cc * 128 + bb]);
            }
        }
#pragma unroll
        for (int kk = 0; kk < 2; ++kk)
#pragma unroll
            for (int fm = 0; fm < 4; ++fm)
#pragma unroll
                for (int fn = 0; fn < 4; ++fn)
                    acc[fm][fn] = __builtin_amdgcn_mfma_f32_16x16x32_bf16(
                        af[kk][fm], bfr[kk][fn], acc[fm][fn], 0, 0, 0);
    };

    stage(0, 0);
    __syncthreads();
    for (int ks = 0; ks < 8; ++ks) {
        if (ks < 7) stage((ks + 1) & 1, ks + 1);
        compute(ks & 1);
        __syncthreads();
    }

#pragma unroll
    for (int fn = 0; fn < 4; ++fn) {
        int col = bcol + wn * 64 + fn * 16 + (lane & 15);
        float bs = bias[col];
#pragma unroll
        for (int fm = 0; fm < 4; ++fm) {
#pragma unroll
            for (int r4 = 0; r4 < 4; ++r4) {
                int grow = brow + wm * 64 + fm * 16 + (lane >> 4) * 4 + r4;
                if (grow < NN)
                    out[(size_t)grow * UU + col] = acc[fm][fn][r4] + bs;
            }
        }
    }
}

// ---------------- launch ----------------

extern "C" void kernel_launch(void* const* d_in, const int* in_sizes, int n_in,
                              void* d_out, int out_size, void* d_ws, size_t ws_size,
                              hipStream_t stream) {
    const float* x    = (const float*)d_in[0];
    const int*   ei   = (const int*)d_in[1];
    const float* ew   = (const float*)d_in[2];
    const float* Wk   = (const float*)d_in[3];   // [512, 256] row-major
    const float* bias = (const float*)d_in[4];
    float* out = (float*)d_out;

    const int* row = ei;
    const int* col = ei + EE;

    char* ws = (char*)d_ws;
    size_t off = 0;
    auto alloc = [&](size_t bytes) {
        size_t o = off;
        off += (bytes + 255) & ~(size_t)255;
        return o;
    };
    float*          deg_p = (float*)(ws + alloc((size_t)NN * PS * sizeof(float)));
    int*            cnt_p = (int*)  (ws + alloc((size_t)NN * PS * sizeof(int)));
    int*            slot  = (int*)  (ws + alloc((size_t)EE * sizeof(int)));
    float*          dis   = (float*)(ws + alloc((size_t)NN * sizeof(float)));
    int*            offs  = (int*)  (ws + alloc((size_t)(NN + 1) * sizeof(int)));
    int*            bsum  = (int*)  (ws + alloc((size_t)256 * sizeof(int)));
    uint2*          edata = (uint2*)(ws + alloc((size_t)EE * sizeof(uint2)));
    unsigned short* Hcat  = (unsigned short*)(ws + alloc((size_t)NN * KK * sizeof(short)));
    unsigned short* Wt    = (unsigned short*)(ws + alloc((size_t)KK * UU * sizeof(short)));

    hipMemsetAsync(deg_p, 0, (size_t)NN * PS * sizeof(float), stream);
    hipMemsetAsync(cnt_p, 0, (size_t)NN * PS * sizeof(int), stream);

    // fused padded-line atomics + xcast
    k_deg_x<<<(NN * 32 + 255) / 256, 256, 0, stream>>>(row, col, ew, deg_p, cnt_p,
                                                       slot, (const float4*)x, Hcat);
    k_scan1<<<NB, 256, 0, stream>>>(cnt_p, deg_p, dis, offs, bsum);
    k_scan2<<<1, 256, 0, stream>>>(bsum);
    k_scan3<<<NB, 256, 0, stream>>>(offs, bsum);
    k_scatter<<<(EE + 255) / 256, 256, 0, stream>>>(row, col, ew, dis, offs, slot,
                                                    edata, Wk, Wt);

    // propagation: slice s -> s+1
    const int gprop = NN / 4;
    k_prop<<<gprop, 256, 0, stream>>>(offs, edata, Hcat, 0, 1);
    k_prop<<<gprop, 256, 0, stream>>>(offs, edata, Hcat, 1, 2);
    k_prop<<<gprop, 256, 0, stream>>>(offs, edata, Hcat, 2, 3);

    // fused GEMM + bias
    k_gemm<<<391 * 2, 256, 0, stream>>>(Hcat, Wt, bias, out);
}

// Round 14
// 259.222 us; speedup vs baseline: 11.5824x; 1.0120x over previous
//
#include <hip/hip_runtime.h>

// Problem constants (fixed by the reference file)
constexpr int NN = 50000;   // nodes
constexpr int EE = 500000;  // edges
constexpr int FF = 128;     // features
constexpr int UU = 256;     // units
constexpr int KK = 512;     // F*(K+1) concat width

// histogram geometry
constexpr int CHB   = 13;            // log2 chunk
constexpr int CHUNK = 1 << CHB;      // 8192 edges per chunk
constexpr int NCH   = (EE + CHUNK - 1) / CHUNK;  // 62 chunks (62*8192 >= 500000)
constexpr int HALF  = 25000;         // nodes per range (2 ranges)
constexpr int HW    = HALF / 2;      // 12500 packed u32 words per range
constexpr int NW    = NN / 2;        // 25000 words total
constexpr int NBW   = (NW + 255) / 256;   // 98 scan1 blocks
constexpr int NB    = (NN + 255) / 256;   // 196 node blocks

using bf16x8 = __attribute__((ext_vector_type(8))) short;
using f32x4  = __attribute__((ext_vector_type(4))) float;

__device__ inline float bf2f(unsigned short b) {
    unsigned u = (unsigned)b << 16; float f; __builtin_memcpy(&f, &u, 4); return f;
}
__device__ inline unsigned short f2bf(float f) {  // round-to-nearest-even
    unsigned u; __builtin_memcpy(&u, &f, 4);
    u = u + 0x7fffu + ((u >> 16) & 1u);
    return (unsigned short)(u >> 16);
}

typedef __attribute__((address_space(1))) const void GASV;
typedef __attribute__((address_space(3))) void LASV;
__device__ inline void gload_lds16(const void* g, void* l) {
    __builtin_amdgcn_global_load_lds((GASV*)g, (LASV*)l, 16, 0, 0);
}

// ---- k_hist: LDS-private col histogram (packed u16 pairs) + deg atomics ----
// 124 blocks = 62 chunks x 2 node-ranges. Returns local slot per edge.
// Only range-0 blocks issue the deg atomics (once per edge).

__global__ __launch_bounds__(256) void k_hist(const int* __restrict__ row,
                                              const int* __restrict__ col,
                                              const float* __restrict__ ew,
                                              float* __restrict__ deg,
                                              unsigned* __restrict__ partial,
                                              unsigned short* __restrict__ lslot) {
    __shared__ unsigned hist[HW];   // 50 KB
    const int b = blockIdx.x >> 1;  // chunk
    const int r = blockIdx.x & 1;   // node range
    const int t = threadIdx.x;
    for (int i = t; i < HW; i += 256) hist[i] = 0;
    __syncthreads();
    const int beg = b << CHB;
    const int end = min(beg + CHUNK, EE);
    const int base = r * HALF;
    for (int e = beg + t; e < end; e += 256) {
        int c = col[e];
        if (r == 0) atomicAdd(&deg[row[e]], ew[e]);
        if (c >= base && c < base + HALF) {
            int wl = (c - base) >> 1;
            int sh = (c & 1) * 16;
            unsigned old = atomicAdd(&hist[wl], 1u << sh);
            lslot[e] = (unsigned short)((old >> sh) & 0xffffu);
        }
    }
    __syncthreads();
    unsigned* dst = partial + ((size_t)b * 2 + r) * HW;
    for (int i = t; i < HW; i += 256) dst[i] = hist[i];
}

// ---- scan1: per-word cross-chunk prefix (PRE) + node scan + dis ----
// one thread per word (2 nodes); 98 blocks.

__global__ __launch_bounds__(256) void k_scan1(const unsigned* __restrict__ partial,
                                               unsigned* __restrict__ PRE,
                                               const float* __restrict__ deg,
                                               float* __restrict__ dis,
                                               int* __restrict__ offs,
                                               int* __restrict__ bsum) {
    const int t = threadIdx.x;
    const int w = blockIdx.x * 256 + t;
    unsigned run = 0;
    if (w < NW) {
        int r = (w >= HW) ? 1 : 0;
        int wl = w - r * HW;
        for (int b = 0; b < NCH; ++b) {
            PRE[(size_t)b * NW + w] = run;
            run += partial[((size_t)b * 2 + r) * HW + wl];
        }
    }
    const unsigned lo = run & 0xffffu;
    const int wsum = (w < NW) ? (int)((run & 0xffffu) + (run >> 16)) : 0;
    __shared__ int ts[256];
    ts[t] = wsum; __syncthreads();
    for (int d = 1; d < 256; d <<= 1) {
        int a = ts[t]; int bb = (t >= d) ? ts[t - d] : 0;
        __syncthreads(); ts[t] = a + bb; __syncthreads();
    }
    int ex = ts[t] - wsum;
    if (w < NW) {
        int n0 = 2 * w, n1 = 2 * w + 1;
        offs[n0] = ex;
        offs[n1] = ex + (int)lo;
        float d0 = deg[n0];
        dis[n0] = (d0 > 0.f) ? (1.0f / sqrtf(fmaxf(d0, 1e-12f))) : 0.f;
        float d1 = deg[n1];
        dis[n1] = (d1 > 0.f) ? (1.0f / sqrtf(fmaxf(d1, 1e-12f))) : 0.f;
    }
    if (t == 255) bsum[blockIdx.x] = ts[255];
}

__global__ __launch_bounds__(256) void k_scan2(int* __restrict__ bsum) {
    const int t = threadIdx.x;
    int v = (t < NBW) ? bsum[t] : 0;
    __shared__ int ts[256];
    ts[t] = v; __syncthreads();
    for (int d = 1; d < 256; d <<= 1) {
        int a = ts[t]; int bb = (t >= d) ? ts[t - d] : 0;
        __syncthreads(); ts[t] = a + bb; __syncthreads();
    }
    if (t < NBW) bsum[t] = ts[t] - v;
}

__global__ __launch_bounds__(256) void k_scan3(int* __restrict__ offs,
                                               const int* __restrict__ bsum) {
    const int gid = blockIdx.x * 256 + threadIdx.x;
    if (gid < NN) offs[gid] += bsum[gid >> 9];   // 512 nodes per scan1 block
    if (gid == 0) offs[NN] = EE;
}

// ---- scatter (atomic-free) + xcast + wcast, one wide kernel ----

__global__ __launch_bounds__(256) void k_scatter(const int* __restrict__ row,
                                                 const int* __restrict__ col,
                                                 const float* __restrict__ ew,
                                                 const float* __restrict__ dis,
                                                 const int* __restrict__ offs,
                                                 const unsigned* __restrict__ PRE,
                                                 const unsigned short* __restrict__ lslot,
                                                 uint2* __restrict__ edata,
                                                 const float4* __restrict__ x4,
                                                 unsigned short* __restrict__ H,
                                                 const float* __restrict__ W,
                                                 unsigned short* __restrict__ Wt) {
    const int i = blockIdx.x * 256 + threadIdx.x;
    if (i < NN * 32) {   // xcast: x f32 -> Hcat slice 0 bf16
        int n = i >> 5, c4 = i & 31;
        float4 v = x4[i];
        ushort4 o;
        o.x = f2bf(v.x); o.y = f2bf(v.y); o.z = f2bf(v.z); o.w = f2bf(v.w);
        *reinterpret_cast<ushort4*>(H + (size_t)n * KK + c4 * 4) = o;
    }
    if (i < EE) {        // edge scatter
        int rr = row[i], c = col[i];
        int b = i >> CHB;
        unsigned pre = PRE[(size_t)b * NW + (c >> 1)];
        int sl = offs[c] + (int)((pre >> ((c & 1) * 16)) & 0xffffu) + (int)lslot[i];
        float wv = dis[rr] * ew[i] * dis[c];
        uint2 d; d.x = (unsigned)rr; __builtin_memcpy(&d.y, &wv, 4);
        edata[sl] = d;
    }
    if (i < KK * UU) {   // wcast: W [512,256] f32 -> Wt [256,512] bf16
        int k = i >> 8, c = i & 255;
        Wt[(size_t)c * KK + k] = f2bf(W[i]);
    }
}

// ---------------- propagation: 4 edges in flight per wave ----------------

__global__ __launch_bounds__(256) void k_prop(const int* __restrict__ offs,
                                              const uint2* __restrict__ edata,
                                              unsigned short* __restrict__ H,
                                              int sin, int sout) {
    const int wid = (blockIdx.x * 256 + threadIdx.x) >> 6;
    const int lane = threadIdx.x & 63;
    const int g = lane >> 4;
    const int sl = lane & 15;

    const unsigned short* bin = H + (size_t)sin * FF;
    const unsigned short* rowp = bin + (size_t)wid * KK + sl * 8;

    float a[8];
    {
        uint4 s4 = *reinterpret_cast<const uint4*>(rowp);
        const unsigned sw[4] = {s4.x, s4.y, s4.z, s4.w};
#pragma unroll
        for (int j = 0; j < 8; ++j) {
            float v = bf2f((unsigned short)(sw[j >> 1] >> ((j & 1) * 16)));
            a[j] = (g == 0) ? v : 0.f;
        }
    }

    const int beg = offs[wid], end = offs[wid + 1];
    int e = beg + g;
    for (; e + 4 < end; e += 8) {
        uint2 d0 = edata[e], d1 = edata[e + 4];
        float w0, w1; __builtin_memcpy(&w0, &d0.y, 4); __builtin_memcpy(&w1, &d1.y, 4);
        uint4 v0 = *reinterpret_cast<const uint4*>(bin + (size_t)d0.x * KK + sl * 8);
        uint4 v1 = *reinterpret_cast<const uint4*>(bin + (size_t)d1.x * KK + sl * 8);
        const unsigned u0[4] = {v0.x, v0.y, v0.z, v0.w};
        const unsigned u1[4] = {v1.x, v1.y, v1.z, v1.w};
#pragma unroll
        for (int j = 0; j < 8; ++j)
            a[j] += bf2f((unsigned short)(u0[j >> 1] >> ((j & 1) * 16))) * w0
                  + bf2f((unsigned short)(u1[j >> 1] >> ((j & 1) * 16))) * w1;
    }
    if (e < end) {
        uint2 d0 = edata[e];
        float w0; __builtin_memcpy(&w0, &d0.y, 4);
        uint4 v0 = *reinterpret_cast<const uint4*>(bin + (size_t)d0.x * KK + sl * 8);
        const unsigned u0[4] = {v0.x, v0.y, v0.z, v0.w};
#pragma unroll
        for (int j = 0; j < 8; ++j)
            a[j] += bf2f((unsigned short)(u0[j >> 1] >> ((j & 1) * 16))) * w0;
    }

#pragma unroll
    for (int j = 0; j < 8; ++j) {
        a[j] += __shfl_xor(a[j], 16);
        a[j] += __shfl_xor(a[j], 32);
    }

    if (lane < 16) {
        uint4 o;
        o.x = (unsigned)f2bf(a[0]) | ((unsigned)f2bf(a[1]) << 16);
        o.y = (unsigned)f2bf(a[2]) | ((unsigned)f2bf(a[3]) << 16);
        o.z = (unsigned)f2bf(a[4]) | ((unsigned)f2bf(a[5]) << 16);
        o.w = (unsigned)f2bf(a[6]) | ((unsigned)f2bf(a[7]) << 16);
        *reinterpret_cast<uint4*>(H + (size_t)sout * FF + (size_t)wid * KK + sl * 8) = o;
    }
}

// ---------------- fused MFMA GEMM: out = Hcat @ Wk + bias ----------------
// grid 784: id = 16q + 8*half + r -> row-tile i = 8q + r, col-tile = half.
// Both col-tiles of a row-tile share (id mod 8) -> same XCD L2 for A panel.

__global__ __launch_bounds__(256, 2) void k_gemm(const unsigned short* __restrict__ H,
                                                 const unsigned short* __restrict__ Wt,
                                                 const float* __restrict__ bias,
                                                 float* __restrict__ out) {
    const int q = blockIdx.x >> 4;
    const int r = blockIdx.x & 7;
    const int half = (blockIdx.x >> 3) & 1;
    const int itile = q * 8 + r;
    if (itile >= 391) return;

    __shared__ __align__(16) char As[2][128 * 128];
    __shared__ __align__(16) char Bs[2][128 * 128];
    const int t = threadIdx.x;
    const int lane = t & 63;
    const int wv = t >> 6;
    const int wm = wv >> 1;
    const int wn = wv & 1;
    const int brow = itile * 128;
    const int bcol = half * 128;

    const int r8  = lane >> 3;
    const int b16 = (lane & 7) * 16;

    f32x4 acc[4][4] = {};

    auto stage = [&](int buf, int ks) {
#pragma unroll
        for (int i = 0; i < 8; ++i) {
            int c = wv * 8 + i;
            if (c < 16) {
                int rr = c * 8 + r8;
                int gr = brow + rr; if (gr >= NN) gr = NN - 1;
                const char* src = (const char*)H + (size_t)gr * (KK * 2) + ks * 128
                                  + (b16 ^ ((rr & 7) << 4));
                gload_lds16(src, &As[buf][c * 1024]);
            } else {
                int cc = (c - 16) * 8 + r8;
                int gc = bcol + cc;
                const char* src = (const char*)Wt + (size_t)gc * (KK * 2) + ks * 128
                                  + (b16 ^ ((cc & 7) << 4));
                gload_lds16(src, &Bs[buf][(c - 16) * 1024]);
            }
        }
    };

    auto compute = [&](int buf) {
        bf16x8 af[2][4], bfr[2][4];
#pragma unroll
        for (int kk = 0; kk < 2; ++kk) {
#pragma unroll
            for (int f = 0; f < 4; ++f) {
                int rr = wm * 64 + f * 16 + (lane & 15);
                int ba = (kk * 64 + (lane >> 4) * 16) ^ ((rr & 7) << 4);
                af[kk][f] = *reinterpret_cast<const bf16x8*>(&As[buf][rr * 128 + ba]);
                int cc = wn * 64 + f * 16 + (lane & 15);
                int bb = (kk * 64 + (lane >> 4) * 16) ^ ((cc & 7) << 4);
                bfr[kk][f] = *reinterpret_cast<const bf16x8*>(&Bs[buf][cc * 128 + bb]);
            }
        }
#pragma unroll
        for (int kk = 0; kk < 2; ++kk)
#pragma unroll
            for (int fm = 0; fm < 4; ++fm)
#pragma unroll
                for (int fn = 0; fn < 4; ++fn)
                    acc[fm][fn] = __builtin_amdgcn_mfma_f32_16x16x32_bf16(
                        af[kk][fm], bfr[kk][fn], acc[fm][fn], 0, 0, 0);
    };

    stage(0, 0);
    __syncthreads();
    for (int ks = 0; ks < 8; ++ks) {
        if (ks < 7) stage((ks + 1) & 1, ks + 1);
        compute(ks & 1);
        __syncthreads();
    }

#pragma unroll
    for (int fn = 0; fn < 4; ++fn) {
        int cg = bcol + wn * 64 + fn * 16 + (lane & 15);
        float bs = bias[cg];
#pragma unroll
        for (int fm = 0; fm < 4; ++fm) {
#pragma unroll
            for (int r4 = 0; r4 < 4; ++r4) {
                int grow = brow + wm * 64 + fm * 16 + (lane >> 4) * 4 + r4;
                if (grow < NN)
                    out[(size_t)grow * UU + cg] = acc[fm][fn][r4] + bs;
            }
        }
    }
}

// ---------------- launch ----------------

extern "C" void kernel_launch(void* const* d_in, const int* in_sizes, int n_in,
                              void* d_out, int out_size, void* d_ws, size_t ws_size,
                              hipStream_t stream) {
    const float* x    = (const float*)d_in[0];
    const int*   ei   = (const int*)d_in[1];
    const float* ew   = (const float*)d_in[2];
    const float* Wk   = (const float*)d_in[3];   // [512, 256] row-major
    const float* bias = (const float*)d_in[4];
    float* out = (float*)d_out;

    const int* row = ei;
    const int* col = ei + EE;

    char* ws = (char*)d_ws;
    size_t off = 0;
    auto alloc = [&](size_t bytes) {
        size_t o = off;
        off += (bytes + 255) & ~(size_t)255;
        return o;
    };
    float*          deg     = (float*)(ws + alloc((size_t)NN * sizeof(float)));
    float*          dis     = (float*)(ws + alloc((size_t)NN * sizeof(float)));
    int*            offs    = (int*)  (ws + alloc((size_t)(NN + 1) * sizeof(int)));
    int*            bsum    = (int*)  (ws + alloc((size_t)256 * sizeof(int)));
    unsigned*       partial = (unsigned*)(ws + alloc((size_t)NCH * 2 * HW * sizeof(unsigned)));
    unsigned*       PRE     = (unsigned*)(ws + alloc((size_t)NCH * NW * sizeof(unsigned)));
    unsigned short* lslot   = (unsigned short*)(ws + alloc((size_t)EE * sizeof(short)));
    uint2*          edata   = (uint2*)(ws + alloc((size_t)EE * sizeof(uint2)));
    unsigned short* Hcat    = (unsigned short*)(ws + alloc((size_t)NN * KK * sizeof(short)));
    unsigned short* Wt      = (unsigned short*)(ws + alloc((size_t)KK * UU * sizeof(short)));

    hipMemsetAsync(deg, 0, (size_t)NN * sizeof(float), stream);

    // CSR build: LDS histogram (cnt halved to LDS) + deg atomics
    k_hist<<<NCH * 2, 256, 0, stream>>>(row, col, ew, deg, partial, lslot);
    k_scan1<<<NBW, 256, 0, stream>>>(partial, PRE, deg, dis, offs, bsum);
    k_scan2<<<1, 256, 0, stream>>>(bsum);
    k_scan3<<<NB, 256, 0, stream>>>(offs, bsum);
    k_scatter<<<(NN * 32 + 255) / 256, 256, 0, stream>>>(row, col, ew, dis, offs,
                                                         PRE, lslot, edata,
                                                         (const float4*)x, Hcat, Wk, Wt);

    // propagation: slice s -> s+1
    const int gprop = NN / 4;
    k_prop<<<gprop, 256, 0, stream>>>(offs, edata, Hcat, 0, 1);
    k_prop<<<gprop, 256, 0, stream>>>(offs, edata, Hcat, 1, 2);
    k_prop<<<gprop, 256, 0, stream>>>(offs, edata, Hcat, 2, 3);

    // fused GEMM + bias (pairing-swizzled grid)
    k_gemm<<<784, 256, 0, stream>>>(Hcat, Wt, bias, out);
}